// Round 6
// baseline (1003.540 us; speedup 1.0000x reference)
//
#include <hip/hip_runtime.h>
#include <utility>

// SICE head for MI355X (gfx950) — round 6.
// R6: (1) k_conv split-K (4 chunks of 512): K-loop 64->16 iters, grid 1664,
// f32 partials -> k_red (sum + fused BN stats, 2 atomics/block).
// (2) Symmetric-output mm_ns/k_gram: all chain matmuls have symmetric
// operands and outputs; compute 20/32 tiles (tr>=2tc), mirror remainder via
// LDS transpose (single-writer: mirror (C,R) iff tile(C,R) not kept).
// mm keeps R5 numerics (A split hi/lo, B hi only).

typedef unsigned short u16;
typedef __attribute__((ext_vector_type(8))) __bf16 bf16x8;
typedef __attribute__((ext_vector_type(8))) _Float16 f16x8;
typedef __attribute__((ext_vector_type(4))) float f32x4;

#define DEV __device__ __forceinline__

DEV u16 f2bf(float f) {
  unsigned x = __float_as_uint(f);
  x += 0x7fffu + ((x >> 16) & 1u);
  return (u16)(x >> 16);
}
DEV float bf2f(u16 h) { return __uint_as_float(((unsigned)h) << 16); }

// sb float-index layout
#define SB_SUM   0
#define SB_SSQ   256
#define SB_IJ    512
#define SB_TRC   768
#define SB_TR2   800
#define SB_TR3   832
#define SB_TRL   864
#define SB_DEN   896
#define SB_IJSUM 928

// ---------------- prep: w -> fp16, init sb ----------------
__global__ __launch_bounds__(256) void k_prep(const float* __restrict__ w,
                                              const float* __restrict__ jitter,
                                              _Float16* __restrict__ w_half,
                                              float* __restrict__ sb) {
  int gid = blockIdx.x * 256 + threadIdx.x;
  if (gid < 256 * 2048) w_half[gid] = (_Float16)w[gid];
  if (blockIdx.x == 0) {
    int t = threadIdx.x;
    sb[SB_SUM + t] = 0.f;
    sb[SB_SSQ + t] = 0.f;
    float ij = 1e-10f + 1e-9f * jitter[t];
    sb[SB_IJ + t] = ij;
    if (t < 160) sb[SB_TRC + t] = 0.f;
    __shared__ float red[256];
    red[t] = ij; __syncthreads();
    for (int off = 128; off > 0; off >>= 1) {
      if (t < off) red[t] += red[t + off];
      __syncthreads();
    }
    if (t == 0) sb[SB_IJSUM] = red[0];
  }
}

// ---------------- conv split-K: yp[kc][b][d][hw] = w@x chunk ----------
// grid 1664 = (4 kc x 13 ht) x 32 b. Tile M=256 x N=64, Kchunk=512, BK=32.
__global__ __launch_bounds__(256) void k_conv(const _Float16* __restrict__ w_half,
                                              const float* __restrict__ x,
                                              float* __restrict__ yp) {
  int xb = blockIdx.x;
  int b = xb & 31;
  int rest = xb >> 5;              // 0..51
  int kc = rest / 13, ht = rest % 13;
  int hw0 = ht * 64;
  int kbase = kc * 512;
  int t = threadIdx.x;
  int wv = t >> 6, lane = t & 63, m = lane & 15, quad = lane >> 4;
  __shared__ _Float16 lsA[256 * 40];
  __shared__ _Float16 lsB[64 * 40];
  f32x4 acc[4][4];
#pragma unroll
  for (int i = 0; i < 4; ++i)
#pragma unroll
    for (int j = 0; j < 4; ++j) acc[i][j] = (f32x4){0.f, 0.f, 0.f, 0.f};
  // A stage: thread t -> row t, 4 uint4 (64B of one row)
  const _Float16* wp = w_half + (size_t)t * 2048 + kbase;
  // B stage: hwB = t&63, cg = t>>6 (4 groups x 8 c)
  int hwB = t & 63, cg = t >> 6;
  bool okB = (hw0 + hwB) < 784;
  const float* xp = x + ((size_t)b * 2048 + kbase + cg * 8) * 784 + hw0 + hwB;
  uint4 ra[4];
  float rb[8];
#pragma unroll
  for (int s = 0; s < 4; ++s) ra[s] = *(const uint4*)(wp + s * 8);
#pragma unroll
  for (int j = 0; j < 8; ++j) rb[j] = okB ? xp[(size_t)j * 784] : 0.f;
  for (int it = 0; it < 16; ++it) {
    if (it) __syncthreads();
#pragma unroll
    for (int s = 0; s < 4; ++s) *(uint4*)&lsA[t * 40 + s * 8] = ra[s];
    {
      union { f16x8 h; uint4 u; } pk;
#pragma unroll
      for (int j = 0; j < 8; ++j) pk.h[j] = (_Float16)rb[j];
      *(uint4*)&lsB[hwB * 40 + cg * 8] = pk.u;
    }
    __syncthreads();
    if (it < 15) {
      int k0 = (it + 1) * 32;
#pragma unroll
      for (int s = 0; s < 4; ++s) ra[s] = *(const uint4*)(wp + k0 + s * 8);
#pragma unroll
      for (int j = 0; j < 8; ++j)
        rb[j] = okB ? xp[((size_t)k0 + j) * 784] : 0.f;
    }
    f16x8 af[4], bfg[4];
#pragma unroll
    for (int i = 0; i < 4; ++i)
      af[i] = *(const f16x8*)&lsA[(wv * 64 + i * 16 + m) * 40 + quad * 8];
#pragma unroll
    for (int j = 0; j < 4; ++j)
      bfg[j] = *(const f16x8*)&lsB[(j * 16 + m) * 40 + quad * 8];
#pragma unroll
    for (int i = 0; i < 4; ++i)
#pragma unroll
      for (int j = 0; j < 4; ++j)
        acc[i][j] = __builtin_amdgcn_mfma_f32_16x16x32_f16(af[i], bfg[j], acc[i][j], 0, 0, 0);
  }
  float* out = yp + (size_t)(kc * 32 + b) * 256 * 784;
#pragma unroll
  for (int i = 0; i < 4; ++i)
#pragma unroll
    for (int j = 0; j < 4; ++j)
#pragma unroll
      for (int r = 0; r < 4; ++r) {
        int R = wv * 64 + i * 16 + quad * 4 + r;
        int hwc = hw0 + j * 16 + m;
        if (hwc < 784) out[(size_t)R * 784 + hwc] = acc[i][j][r];
      }
}

// ---------------- k_red: y = sum_k yp[k] (f16) + BN stats ----------------
// grid 8192 = 256 d x 32 b (b low bits).
__global__ __launch_bounds__(256) void k_red(const float* __restrict__ yp,
                                             _Float16* __restrict__ y,
                                             float* __restrict__ sb) {
  int xb = blockIdx.x;
  int b = xb & 31, d = xb >> 5, t = threadIdx.x;
  const size_t cs = (size_t)32 * 256 * 784;
  const float* p = yp + ((size_t)b * 256 + d) * 784;
  _Float16* yo = y + ((size_t)b * 256 + d) * 784;
  float s = 0.f, q = 0.f;
#pragma unroll
  for (int it = 0; it < 4; ++it) {
    int idx = it * 256 + t;
    if (idx < 784) {
      float v = p[idx] + p[cs + idx] + p[2 * cs + idx] + p[3 * cs + idx];
      yo[idx] = (_Float16)v;
      s += v; q += v * v;
    }
  }
  __shared__ float rs[256], rq[256];
  rs[t] = s; rq[t] = q; __syncthreads();
  for (int off = 128; off > 0; off >>= 1) {
    if (t < off) { rs[t] += rs[t + off]; rq[t] += rq[t + off]; }
    __syncthreads();
  }
  if (t == 0) {
    atomicAdd(&sb[SB_SUM + d], rs[0]);
    atomicAdd(&sb[SB_SSQ + d], rq[0]);
  }
}

// ---------------- BN finalize+apply + relu + row-center -> yc fp16 --------
__global__ __launch_bounds__(256) void k_bnapply(const _Float16* __restrict__ y,
                                                 const float* __restrict__ gamma,
                                                 const float* __restrict__ beta,
                                                 const float* __restrict__ sb,
                                                 _Float16* __restrict__ yc) {
  int xb = blockIdx.x;
  int d = xb >> 5, b = xb & 31, t = threadIdx.x;
  float mu = sb[SB_SUM + d] * (1.0f / 25088.0f);
  float var = sb[SB_SSQ + d] * (1.0f / 25088.0f) - mu * mu;
  float sc = gamma[d] / sqrtf(var + 1e-5f);
  float sh = beta[d] - mu * sc;
  const _Float16* row = y + ((size_t)b * 256 + d) * 784;
  float v[4];
  float s = 0.f;
#pragma unroll
  for (int i = 0; i < 4; ++i) {
    int idx = t + i * 256;
    float u = 0.f;
    if (idx < 784) u = fmaxf((float)row[idx] * sc + sh, 0.f);
    v[i] = u; s += u;
  }
  __shared__ float red[256];
  red[t] = s; __syncthreads();
  for (int off = 128; off > 0; off >>= 1) {
    if (t < off) red[t] += red[t + off];
    __syncthreads();
  }
  float mean = red[0] * (1.0f / 784.0f);
  _Float16* out = yc + ((size_t)b * 256 + d) * 800;
#pragma unroll
  for (int i = 0; i < 4; ++i) {
    int idx = t + i * 256;
    if (idx < 784) out[idx] = (_Float16)(v[i] - mean);
  }
  if (t < 16) out[784 + t] = (_Float16)0.f;
}

// symmetric tile tables: 20 tiles (tr 32-row, tc 64-col) with tr >= 2tc
__device__ __constant__ signed char SYM_TR[20] = {0,1,2,3,4,5,6,7, 2,3,4,5,6,7, 4,5,6,7, 6,7};
__device__ __constant__ signed char SYM_TC[20] = {0,0,0,0,0,0,0,0, 1,1,1,1,1,1, 2,2,2,2, 3,3};

// ---------------- gram: C = yc@yc^T/784 — sym tiles + mirror -------------
// grid 640 = 20 tiles x 32 b.
__global__ __launch_bounds__(256) void k_gram(const _Float16* __restrict__ yc,
                                              float* __restrict__ C,
                                              float* __restrict__ sb) {
  int xb = blockIdx.x;
  int b = xb & 31, p = xb >> 5;
  int tr = SYM_TR[p], tc = SYM_TC[p];
  int t = threadIdx.x, wv = t >> 6, lane = t & 63, m = lane & 15, quad = lane >> 4;
  __shared__ _Float16 lsA[2][32 * 40];
  __shared__ _Float16 lsB[2][64 * 40];
  __shared__ float lsT[32][65];
  f32x4 acc[2];
  acc[0] = (f32x4){0.f, 0.f, 0.f, 0.f};
  acc[1] = (f32x4){0.f, 0.f, 0.f, 0.f};
  int row = t >> 2, seg = t & 3;
  const _Float16* base = yc + (size_t)b * 256 * 800;
  const _Float16* Bp = base + (size_t)(tc * 64 + row) * 800 + seg * 8;
  const _Float16* Ap = base + (size_t)(tr * 32 + row) * 800 + seg * 8;
  bool doA = row < 32;
  uint4 rB = *(const uint4*)(Bp);
  uint4 rA = doA ? *(const uint4*)(Ap) : (uint4){0, 0, 0, 0};
  int ar = (wv >> 1) * 16, bcl = (wv & 1) * 32;
  for (int ks = 0; ks < 25; ++ks) {
    int buf = ks & 1;
    int lo = row * 40 + seg * 8;
    *(uint4*)&lsB[buf][lo] = rB;
    if (doA) *(uint4*)&lsA[buf][lo] = rA;
    if (ks < 24) {
      int k0 = (ks + 1) * 32;
      rB = *(const uint4*)(Bp + k0);
      if (doA) rA = *(const uint4*)(Ap + k0);
    }
    __syncthreads();
    f16x8 a0 = *(const f16x8*)&lsA[buf][(ar + m) * 40 + quad * 8];
    f16x8 b0 = *(const f16x8*)&lsB[buf][(bcl + m) * 40 + quad * 8];
    f16x8 b1 = *(const f16x8*)&lsB[buf][(bcl + 16 + m) * 40 + quad * 8];
    acc[0] = __builtin_amdgcn_mfma_f32_16x16x32_f16(a0, b0, acc[0], 0, 0, 0);
    acc[1] = __builtin_amdgcn_mfma_f32_16x16x32_f16(a0, b1, acc[1], 0, 0, 0);
  }
  const float inv = 1.0f / 784.0f;
  float* Cb = C + (size_t)b * 65536;
#pragma unroll
  for (int j = 0; j < 2; ++j)
#pragma unroll
    for (int r = 0; r < 4; ++r) {
      int rl = ar + quad * 4 + r, cl = bcl + j * 16 + m;
      int R = tr * 32 + rl, Cc = tc * 64 + cl;
      float v = acc[j][r] * inv;
      Cb[(size_t)R * 256 + Cc] = v;
      lsT[rl][cl] = v;
      if (R == Cc) atomicAdd(&sb[SB_TRC + b], v);
    }
  __syncthreads();
  int tcm2 = 2 * (tr >> 1);
#pragma unroll
  for (int it = 0; it < 8; ++it) {
    int idx = it * 256 + t;
    int r2 = idx & 31, c2 = idx >> 5;
    int trm = 2 * tc + (c2 >> 5);
    if (trm < tcm2) {
      int Rm = 64 * tc + c2, Cm = 32 * tr + r2;
      Cb[(size_t)Rm * 256 + Cm] = lsT[r2][c2];
    }
  }
}

// ---------------- prep A and ZY (split bf16); mode0 also writes symC ------
__global__ __launch_bounds__(256) void k_prepAZY(const float* __restrict__ src,
                                                 float* __restrict__ symC,
                                                 u16* __restrict__ Ah, u16* __restrict__ Al,
                                                 u16* __restrict__ ZYh, u16* __restrict__ ZYl,
                                                 float* __restrict__ sb, int slot, int mode) {
  int xb = blockIdx.x;
  int ig = xb >> 5, b = xb & 31, j = threadIdx.x;
  float trv = (mode == 0) ? 1.0f : sb[slot + b];
  float denom = trv + sb[SB_IJSUM];
  if (ig == 0 && j == 0) sb[SB_DEN + b] = denom;
  float trC = (mode == 0) ? sb[SB_TRC + b] : 1.0f;
#pragma unroll
  for (int ii = 0; ii < 8; ++ii) {
    int i = ig * 8 + ii;
    size_t idx = ((size_t)b * 256 + i) * 256 + j;
    float v;
    if (mode == 0) {
      float vij = src[idx] / trC;
      float vji = src[((size_t)b * 256 + j) * 256 + i] / trC;
      symC[idx] = 0.5f * (vij + vji);
      v = vij;
    } else {
      v = src[idx];
    }
    if (i == j) v += sb[SB_IJ + i];
    float A = v / denom;
    u16 h = f2bf(A);
    Ah[idx] = h; Al[idx] = f2bf(A - bf2f(h));
    float zy = 0.5f * ((i == j ? 3.0f : 0.0f) - A);
    h = f2bf(zy);
    ZYh[idx] = h; ZYl[idx] = f2bf(zy - bf2f(h));
  }
}

// ---------------- batched matmul C = (Ah+Al)@Bh — sym tiles + mirror ------
struct MMArgs {
  const u16* Ah; const u16* Al; const u16* Bh;
  u16* Oh; u16* Ol; float* Of; float* tr; int emode;
};

__global__ __launch_bounds__(256) void mm_ns(MMArgs g0, MMArgs g1,
                                             const float* __restrict__ sb) {
  int xb = blockIdx.x;
  int b = xb & 31;
  int rest = xb >> 5;
  MMArgs g = (rest < 20) ? g0 : g1;
  int p = (rest < 20) ? rest : rest - 20;
  int tr = SYM_TR[p], tc = SYM_TC[p];
  int t = threadIdx.x, wv = t >> 6, lane = t & 63, m = lane & 15, quad = lane >> 4;
  __shared__ u16 lsAh[2][32 * 40], lsAl[2][32 * 40];
  __shared__ u16 lsBh[2][64 * 40];
  __shared__ float lsT[32][65];
  f32x4 acc[2];
  acc[0] = (f32x4){0.f, 0.f, 0.f, 0.f};
  acc[1] = (f32x4){0.f, 0.f, 0.f, 0.f};
  int row = t >> 2, seg = t & 3;
  size_t mb = (size_t)b * 65536;
  size_t bO = mb + (size_t)(tc * 64 + row) * 256 + seg * 8;
  size_t aO = mb + (size_t)(tr * 32 + row) * 256 + seg * 8;
  bool doA = row < 32;
  uint4 rBh = *(const uint4*)(g.Bh + bO);
  uint4 rAh = doA ? *(const uint4*)(g.Ah + aO) : (uint4){0, 0, 0, 0};
  uint4 rAl = doA ? *(const uint4*)(g.Al + aO) : (uint4){0, 0, 0, 0};
  int ar = (wv >> 1) * 16, bcl = (wv & 1) * 32;
  for (int ks = 0; ks < 8; ++ks) {
    int buf = ks & 1;
    int lo = row * 40 + seg * 8;
    *(uint4*)&lsBh[buf][lo] = rBh;
    if (doA) {
      *(uint4*)&lsAh[buf][lo] = rAh;
      *(uint4*)&lsAl[buf][lo] = rAl;
    }
    if (ks < 7) {
      int k0 = (ks + 1) * 32;
      rBh = *(const uint4*)(g.Bh + bO + k0);
      if (doA) {
        rAh = *(const uint4*)(g.Ah + aO + k0);
        rAl = *(const uint4*)(g.Al + aO + k0);
      }
    }
    __syncthreads();
    bf16x8 ah = *(const bf16x8*)&lsAh[buf][(ar + m) * 40 + quad * 8];
    bf16x8 al = *(const bf16x8*)&lsAl[buf][(ar + m) * 40 + quad * 8];
    bf16x8 bh0 = *(const bf16x8*)&lsBh[buf][(bcl + m) * 40 + quad * 8];
    bf16x8 bh1 = *(const bf16x8*)&lsBh[buf][(bcl + 16 + m) * 40 + quad * 8];
    acc[0] = __builtin_amdgcn_mfma_f32_16x16x32_bf16(ah, bh0, acc[0], 0, 0, 0);
    acc[0] = __builtin_amdgcn_mfma_f32_16x16x32_bf16(al, bh0, acc[0], 0, 0, 0);
    acc[1] = __builtin_amdgcn_mfma_f32_16x16x32_bf16(ah, bh1, acc[1], 0, 0, 0);
    acc[1] = __builtin_amdgcn_mfma_f32_16x16x32_bf16(al, bh1, acc[1], 0, 0, 0);
  }
  float scl = 1.0f;
  if (g.emode == 2) scl = 1.0f / sqrtf(sb[SB_DEN + b]);
#pragma unroll
  for (int j = 0; j < 2; ++j)
#pragma unroll
    for (int r = 0; r < 4; ++r) {
      int rl = ar + quad * 4 + r, cl = bcl + j * 16 + m;
      int R = tr * 32 + rl, Cc = tc * 64 + cl;
      float v = acc[j][r];
      if (g.emode == 1) v = 0.5f * ((R == Cc ? 3.0f : 0.0f) - v);
      else if (g.emode == 2) v = v * scl;
      lsT[rl][cl] = v;
      size_t oidx = mb + (size_t)R * 256 + Cc;
      if (g.emode == 3) {
        g.Of[oidx] = v;
        if (R == Cc && g.tr) atomicAdd(g.tr + b, v);
      } else {
        u16 h = f2bf(v);
        g.Oh[oidx] = h;
        g.Ol[oidx] = f2bf(v - bf2f(h));
      }
    }
  __syncthreads();
  int tcm2 = 2 * (tr >> 1);
#pragma unroll
  for (int it = 0; it < 8; ++it) {
    int idx = it * 256 + t;
    int r2 = idx & 31, c2 = idx >> 5;
    int trm = 2 * tc + (c2 >> 5);
    if (trm < tcm2) {
      int Rm = 64 * tc + c2, Cm = 32 * tr + r2;
      size_t oidx = mb + (size_t)Rm * 256 + Cm;
      float v = lsT[r2][c2];
      if (g.emode == 3) {
        g.Of[oidx] = v;
      } else {
        u16 h = f2bf(v);
        g.Oh[oidx] = h;
        g.Ol[oidx] = f2bf(v - bf2f(h));
      }
    }
  }
}

// ---------------- SICE elementwise update, tile-symmetric ----------------
__global__ __launch_bounds__(256) void k_sice(const float* __restrict__ LLT,
                                              const float* __restrict__ P,
                                              const float* __restrict__ symC,
                                              float* __restrict__ out,
                                              float* __restrict__ sb, int slot,
                                              float dec) {
  int xb = blockIdx.x;
  int b = xb & 31, p = xb >> 5;
  const int TRt[10] = {0, 0, 0, 0, 1, 1, 1, 2, 2, 3};
  const int TCt[10] = {0, 1, 2, 3, 1, 2, 3, 2, 3, 3};
  int tr = TRt[p], tc = TCt[p];
  __shared__ float ft[64][65];
  __shared__ float ot[64][65];
  int t = threadIdx.x;
  size_t base = (size_t)b * 65536;
#pragma unroll 4
  for (int it = 0; it < 16; ++it) {
    int idx = it * 256 + t;
    int r = idx >> 6, c = idx & 63;
    size_t o = base + (size_t)(tc * 64 + r) * 256 + tr * 64 + c;
    float L = LLT[o];
    float g = symC[o] - P[o];
    float f = fmaxf(fmaxf(L, 0.f) - dec * (g + 0.07f), 0.f) -
              fmaxf(fmaxf(-L, 0.f) - dec * (-g + 0.07f), 0.f);
    ft[r][c] = f;
  }
  __syncthreads();
  float tsum = 0.f;
#pragma unroll 4
  for (int it = 0; it < 16; ++it) {
    int idx = it * 256 + t;
    int r = idx >> 6, c = idx & 63;
    size_t o = base + (size_t)(tr * 64 + r) * 256 + tc * 64 + c;
    float L = LLT[o];
    float g = symC[o] - P[o];
    float f = fmaxf(fmaxf(L, 0.f) - dec * (g + 0.07f), 0.f) -
              fmaxf(fmaxf(-L, 0.f) - dec * (-g + 0.07f), 0.f);
    float val = 0.5f * (f + ft[c][r]);
    out[o] = val;
    ot[r][c] = val;
    if (tr == tc && r == c) tsum += val;
  }
  if (tr == tc) {
    if (tsum != 0.f) atomicAdd(&sb[slot + b], tsum);
  } else {
    __syncthreads();
#pragma unroll 4
    for (int it = 0; it < 16; ++it) {
      int idx = it * 256 + t;
      int r = idx >> 6, c = idx & 63;
      size_t o = base + (size_t)(tc * 64 + r) * 256 + tr * 64 + c;
      out[o] = ot[c][r];
    }
  }
}

// ---------------- triu-vec output ----------------
__global__ __launch_bounds__(256) void k_out(const float* __restrict__ LLT,
                                             const float* __restrict__ sb,
                                             float* __restrict__ out) {
  int xb = blockIdx.x;
  int i = xb >> 5, b = xb & 31, j = threadIdx.x;
  if (j < i) return;
  float inv = 1.0f / sqrtf(sb[SB_TRL + b]);
  int tl = i * 256 - (i * (i - 1)) / 2 + (j - i);
  out[(size_t)b * 32896 + tl] = LLT[((size_t)b * 256 + i) * 256 + j] * inv;
}

extern "C" void kernel_launch(void* const* d_in, const int* in_sizes, int n_in,
                              void* d_out, int out_size, void* d_ws, size_t ws_size,
                              hipStream_t stream) {
  const float* x = (const float*)d_in[0];
  const float* w = (const float*)d_in[1];
  const float* gamma = (const float*)d_in[2];
  const float* beta = (const float*)d_in[3];
  const float* jitter = (const float*)d_in[4];
  char* ws = (char*)d_ws;

  _Float16* w_half = (_Float16*)(ws + 0);            // 1 MB
  float* sb = (float*)(ws + (1 << 20));              // 4 KB
  _Float16* y = (_Float16*)(ws + (2 << 20));         // 12.85 MB
  _Float16* yc = (_Float16*)(ws + (16 << 20));       // 13.1 MB
  char* ov = ws + (32 << 20);
  // yp (102.8 MB) overlays the whole NS region — dead after k_red.
  float* yp = (float*)(ov);
  float* Craw = (float*)(ov + 0);
  float* symC = (float*)(ov + 8388608);
  float* LLTa = (float*)(ov + 16777216);
  float* P = (float*)(ov + 25165824);
  float* LLTb = (float*)(ov + 33554432);
  u16* bf[12];
  for (int i = 0; i < 12; ++i) bf[i] = (u16*)(ov + 41943040 + (size_t)i * 4194304);

  k_prep<<<2048, 256, 0, stream>>>(w, jitter, w_half, sb);
  k_conv<<<1664, 256, 0, stream>>>(w_half, x, yp);
  k_red<<<8192, 256, 0, stream>>>(yp, y, sb);
  k_bnapply<<<8192, 256, 0, stream>>>(y, gamma, beta, sb, yc);
  k_gram<<<640, 256, 0, stream>>>(yc, Craw, sb);

  auto run_ns = [&](const float* src, int mode, int slot_in, float* Pout,
                    float* tr_out) {
    k_prepAZY<<<1024, 256, 0, stream>>>(src, symC, bf[0], bf[1], bf[2], bf[3], sb, slot_in, mode);
    u16 *Ah = bf[0], *Al = bf[1], *ZYh = bf[2], *ZYl = bf[3];
    u16 *Yh = bf[4], *Yl = bf[5], *Z2h = bf[6], *Z2l = bf[7];
    u16 *Th = bf[8], *Tl = bf[9], *zzh = bf[10], *zzl = bf[11];
    MMArgs m1{Ah, Al, ZYh, Yh, Yl, nullptr, nullptr, 0};       // Y = A@ZY
    mm_ns<<<640, 256, 0, stream>>>(m1, m1, sb);
    u16 *Ych = Yh, *Ycl = Yl, *Yah = Ah, *Yal = Al;
    u16 *Zch = ZYh, *Zcl = ZYl, *Zah = Z2h, *Zal = Z2l;
    for (int it = 0; it < 5; ++it) {
      MMArgs mt{Zch, Zcl, Ych, Th, Tl, nullptr, nullptr, 1};   // T = 0.5(3I-Z@Y)
      mm_ns<<<640, 256, 0, stream>>>(mt, mt, sb);
      MMArgs my{Ych, Ycl, Th, Yah, Yal, nullptr, nullptr, 0};  // Y' = Y@T
      MMArgs mz{Th, Tl, Zch, Zah, Zal, nullptr, nullptr, 0};   // Z' = T@Z
      mm_ns<<<1280, 256, 0, stream>>>(my, mz, sb);
      std::swap(Ych, Yah); std::swap(Ycl, Yal);
      std::swap(Zch, Zah); std::swap(Zcl, Zal);
    }
    MMArgs mt6{Zch, Zcl, Ych, Th, Tl, nullptr, nullptr, 1};
    mm_ns<<<640, 256, 0, stream>>>(mt6, mt6, sb);
    MMArgs mz7{Th, Tl, Zch, zzh, zzl, nullptr, nullptr, 2};    // zz = T@Z * rsqrt
    mm_ns<<<640, 256, 0, stream>>>(mz7, mz7, sb);
    MMArgs mzz{zzh, zzl, zzh, nullptr, nullptr, Pout, tr_out, 3};  // P = zz@zz
    mm_ns<<<640, 256, 0, stream>>>(mzz, mzz, sb);
  };

  run_ns(Craw, 0, 0, LLTa, sb + SB_TR2);   // LLT init (trace -> TR2)
  run_ns(LLTa, 1, SB_TR2, P, nullptr);     // SICE i=0
  k_sice<<<320, 256, 0, stream>>>(LLTa, P, symC, LLTb, sb, SB_TR3, 5.0f);
  run_ns(LLTb, 1, SB_TR3, P, nullptr);     // SICE i=1
  k_sice<<<320, 256, 0, stream>>>(LLTb, P, symC, LLTa, sb, SB_TRL, 2.5f);
  // SICE i=2: dec=0 -> provable no-op

  k_out<<<8192, 256, 0, stream>>>(LLTa, sb, (float*)d_out);
}